// Round 1
// baseline (938.757 us; speedup 1.0000x reference)
//
#include <hip/hip_runtime.h>
#include <math.h>

#define T_SZ 4096
#define B_SZ 16
#define CIN 256
#define N_H 8
#define D_H 32
#define M_C 16
#define BH_SZ 128
#define TAU 5e-4f
#define RCAP (1<<21)

typedef unsigned char u8;

// ---- workspace layout (bytes) ----
#define O_FWT   0                    // float[256*256] f_w transposed [c][j]
#define O_VWT   262144               // float[256*256]
#define O_PWT   524288               // float[256*256]
#define O_PX    786432               // double[B*16*256] pooled x (mean)
#define O_C64   1310720              // double[B*H*16*32] normalized centers
#define O_C32   1835008              // float  same
#define O_VC    2097152              // float[B*H*16*32] value centers
#define O_COUT  2359296              // float[B*H*16*32] centers_out
#define O_GACC  2621440              // float[128*16*33] scatter accum
#define O_CNT   2891776              // int rescue counter
#define O_LIST  2892032              // uint[RCAP]
#define O_SELM  11280640             // u8[128*4096*2]
#define O_SELW  12329216             // float2[128*4096]
#define O_V     16523520             // float[B*T*256]
// end = 83632384 (~84 MB)

// ---------------- weight transpose ----------------
__global__ void k_transpose(const float* __restrict__ fw, const float* __restrict__ vw,
                            const float* __restrict__ pw, float* __restrict__ fwT,
                            float* __restrict__ vwT, float* __restrict__ pwT){
  int id = blockIdx.x * 256 + threadIdx.x;
  int mat = id >> 16; int rem = id & 65535;
  int j = rem >> 8, c = rem & 255;
  const float* src = (mat == 0) ? fw : ((mat == 1) ? vw : pw);
  float* dst = (mat == 0) ? fwT : ((mat == 1) ? vwT : pwT);
  dst[c * 256 + j] = src[j * 256 + c];
}

// ---------------- fp64 spatial pooling of x ----------------
__global__ void k_pool(const float* __restrict__ x, double* __restrict__ px){
  int b = blockIdx.x >> 4, m = blockIdx.x & 15;
  int pr = m >> 2, pc = m & 3;
  int c = threadIdx.x;
  double s = 0.0;
  for (int i = 0; i < 16; i++){
    int t0 = (pr * 16 + i) * 64 + pc * 16;
    const float* xr = x + ((size_t)t0 * B_SZ + b) * CIN + c;
    for (int jj = 0; jj < 16; jj++)
      s += (double)xr[(size_t)jj * B_SZ * CIN];
  }
  px[(size_t)(b * 16 + m) * 256 + c] = s * (1.0 / 256.0);
}

// ---------------- fp64 centers + value centers ----------------
__global__ void k_centers(const double* __restrict__ px, const float* __restrict__ fwT,
                          const float* __restrict__ vwT, const float* __restrict__ fb,
                          const float* __restrict__ vb, double* __restrict__ c64,
                          float* __restrict__ c32, float* __restrict__ vc){
  int b = blockIdx.x >> 4, m = blockIdx.x & 15;
  int j = threadIdx.x;
  const double* pxr = px + (size_t)(b * 16 + m) * 256;
  double cq = (double)fb[j], cv = (double)vb[j];
  for (int c = 0; c < 256; c++){
    double p = pxr[c];
    cq += p * (double)fwT[c * 256 + j];
    cv += p * (double)vwT[c * 256 + j];
  }
  __shared__ double sq[256];
  __shared__ double snm[8];
  sq[j] = cq * cq;
  __syncthreads();
  int h = j >> 5, d = j & 31;
  if ((j & 31) == 0){
    double ts = 0.0;
    for (int dd = 0; dd < 32; dd++) ts += sq[h * 32 + dd];
    snm[h] = fmax(sqrt(ts), 1e-12);
  }
  __syncthreads();
  double nm = snm[h];
  size_t o = ((size_t)(b * N_H + h) * M_C + m) * D_H + d;
  double ch = cq / nm;
  c64[o] = ch; c32[o] = (float)ch; vc[o] = (float)cv;
}

// ---------------- shared register-blocked GEMM inner (32 rows x 256 cols, K=256) ----------------
__device__ __forceinline__ void gemm_inner(const float (*xs)[260], const float* __restrict__ wT,
                                           int tx, int ty, float acc[8][4]){
  for (int c = 0; c < 256; c += 4){
    const float4 w0 = *(const float4*)(wT + (size_t)(c + 0) * 256 + tx * 4);
    const float4 w1 = *(const float4*)(wT + (size_t)(c + 1) * 256 + tx * 4);
    const float4 w2 = *(const float4*)(wT + (size_t)(c + 2) * 256 + tx * 4);
    const float4 w3 = *(const float4*)(wT + (size_t)(c + 3) * 256 + tx * 4);
#pragma unroll
    for (int rr = 0; rr < 8; rr++){
      const float4 xv = *(const float4*)&xs[ty * 8 + rr][c];
      acc[rr][0] = fmaf(xv.x, w0.x, fmaf(xv.y, w1.x, fmaf(xv.z, w2.x, fmaf(xv.w, w3.x, acc[rr][0]))));
      acc[rr][1] = fmaf(xv.x, w0.y, fmaf(xv.y, w1.y, fmaf(xv.z, w2.y, fmaf(xv.w, w3.y, acc[rr][1]))));
      acc[rr][2] = fmaf(xv.x, w0.z, fmaf(xv.y, w1.z, fmaf(xv.z, w2.z, fmaf(xv.w, w3.z, acc[rr][2]))));
      acc[rr][3] = fmaf(xv.x, w0.w, fmaf(xv.y, w1.w, fmaf(xv.z, w2.w, fmaf(xv.w, w3.w, acc[rr][3]))));
    }
  }
}

// ---------------- q GEMM + similarity + top-2 ----------------
__global__ __launch_bounds__(256, 3) void k_qsim(
    const float* __restrict__ x, const float* __restrict__ fwT, const float* __restrict__ fb,
    const float* __restrict__ c32, const float* __restrict__ salpha, const float* __restrict__ sbeta,
    u8* __restrict__ selm, float2* __restrict__ selw, int* __restrict__ cnt,
    unsigned int* __restrict__ list){
  int b = blockIdx.x >> 7, tt = blockIdx.x & 127;
  __shared__ float xs[32][260];   // x tile, becomes q tile
  __shared__ float cs[8][516];    // normalized centers for this b
  int tid = threadIdx.x;
  for (int k = 0; k < 16; k++){
    int i = k * 256 + tid;
    cs[i >> 9][i & 511] = c32[(size_t)b * 4096 + i];
  }
  for (int i = 0; i < 32; i++){
    int t = tt * 32 + i;
    xs[i][tid] = x[((size_t)t * B_SZ + b) * CIN + tid];
  }
  __syncthreads();
  int tx = tid & 63, ty = tid >> 6;
  float acc[8][4];
#pragma unroll
  for (int rr = 0; rr < 8; rr++){ acc[rr][0] = 0.f; acc[rr][1] = 0.f; acc[rr][2] = 0.f; acc[rr][3] = 0.f; }
  gemm_inner(xs, fwT, tx, ty, acc);
  float4 bb = *(const float4*)(fb + tx * 4);
  __syncthreads();  // all xs reads done, safe to overwrite with q
#pragma unroll
  for (int rr = 0; rr < 8; rr++){
    float4 qv = make_float4(acc[rr][0] + bb.x, acc[rr][1] + bb.y, acc[rr][2] + bb.z, acc[rr][3] + bb.w);
    *(float4*)&xs[ty * 8 + rr][tx * 4] = qv;
  }
  __syncthreads();
  // phase 2: one thread per (token, head)
  int r = tid >> 3, h = tid & 7;
  int t = tt * 32 + r;
  float q[32];
  float ss = 0.f;
#pragma unroll
  for (int d = 0; d < 32; d += 4){
    float4 qv = *(const float4*)&xs[r][h * 32 + d];
    q[d] = qv.x; q[d + 1] = qv.y; q[d + 2] = qv.z; q[d + 3] = qv.w;
    ss += qv.x * qv.x + qv.y * qv.y + qv.z * qv.z + qv.w * qv.w;
  }
  float inv = 1.f / fmaxf(sqrtf(ss), 1e-12f);
  float alpha = salpha[0], beta = sbeta[0];
  float s1 = -1e30f, s2 = -1e30f, s3 = -1e30f; int i1 = 0, i2 = 0;
#pragma unroll
  for (int m = 0; m < 16; m++){
    float dot = 0.f;
#pragma unroll
    for (int d = 0; d < 32; d += 4){
      float4 cv = *(const float4*)&cs[h][m * 32 + d];
      dot = fmaf(q[d], cv.x, fmaf(q[d + 1], cv.y, fmaf(q[d + 2], cv.z, fmaf(q[d + 3], cv.w, dot))));
    }
    float z = beta + alpha * (dot * inv);
    float s = 1.f / (1.f + expf(-z));
    if (s > s1){ s3 = s2; s2 = s1; i2 = i1; s1 = s; i1 = m; }
    else if (s > s2){ s3 = s2; s2 = s; i2 = m; }
    else if (s > s3){ s3 = s; }
  }
  if (s2 - s3 < TAU){
    int idx = atomicAdd(cnt, 1);
    if (idx < RCAP) list[idx] = (((unsigned)(b * N_H + h)) << 12) | (unsigned)t;
  }
  float r1 = s1 * s1, r2 = s2 * s2;
  float den = r1 + r2 + 1e-6f;
  size_t so = (size_t)(b * N_H + h) * T_SZ + t;
  selm[so * 2] = (u8)i1; selm[so * 2 + 1] = (u8)i2;
  selw[so] = make_float2(r1 / den, r2 / den);
}

// ---------------- fp64 rescue for near-tie tokens ----------------
__global__ __launch_bounds__(128, 1) void k_rescue(
    const float* __restrict__ x, const float* __restrict__ fw, const float* __restrict__ fb,
    const double* __restrict__ c64, const float* __restrict__ salpha, const float* __restrict__ sbeta,
    const int* __restrict__ cnt, const unsigned int* __restrict__ list,
    u8* __restrict__ selm, float2* __restrict__ selw){
  __shared__ double qsh[128][33];
  int n = *cnt; if (n > RCAP) n = RCAP;
  double alpha = (double)salpha[0], beta = (double)sbeta[0];
  for (int i = blockIdx.x * 128 + threadIdx.x; i < n; i += gridDim.x * 128){
    unsigned e = list[i];
    int t = e & 4095; int bh = e >> 12; int b = bh >> 3, h = bh & 7;
    const float* xr = x + ((size_t)t * B_SZ + b) * CIN;
    double ss = 0.0;
    for (int d = 0; d < 32; d++){
      const float* wr = fw + (size_t)(h * 32 + d) * CIN;
      double a0 = 0, a1 = 0, a2 = 0, a3 = 0;
      for (int c = 0; c < 256; c += 4){
        a0 += (double)xr[c]     * (double)wr[c];
        a1 += (double)xr[c + 1] * (double)wr[c + 1];
        a2 += (double)xr[c + 2] * (double)wr[c + 2];
        a3 += (double)xr[c + 3] * (double)wr[c + 3];
      }
      double qd = ((a0 + a1) + (a2 + a3)) + (double)fb[h * 32 + d];
      qsh[threadIdx.x][d] = qd;
      ss += qd * qd;
    }
    double inv = 1.0 / fmax(sqrt(ss), 1e-12);
    double s1 = -1e300, s2 = -1e300; int i1 = 0, i2 = 0;
    const double* cb = c64 + (size_t)bh * M_C * D_H;
    for (int m = 0; m < 16; m++){
      double dot = 0.0;
      for (int d = 0; d < 32; d++) dot += qsh[threadIdx.x][d] * cb[m * 32 + d];
      double z = beta + alpha * (dot * inv);
      double s = 1.0 / (1.0 + exp(-z));
      if (s > s1){ s2 = s1; i2 = i1; s1 = s; i1 = m; }
      else if (s > s2){ s2 = s; i2 = m; }
    }
    double r1 = s1 * s1, r2 = s2 * s2, den = r1 + r2 + 1e-6;
    size_t so = (size_t)bh * T_SZ + t;
    selm[so * 2] = (u8)i1; selm[so * 2 + 1] = (u8)i2;
    selw[so] = make_float2((float)(r1 / den), (float)(r2 / den));
  }
}

// ---------------- v GEMM ----------------
__global__ __launch_bounds__(256, 4) void k_vgemm(
    const float* __restrict__ x, const float* __restrict__ wT, const float* __restrict__ bias,
    float* __restrict__ v){
  int b = blockIdx.x >> 7, tt = blockIdx.x & 127;
  __shared__ float xs[32][260];
  int tid = threadIdx.x;
  for (int i = 0; i < 32; i++){
    int t = tt * 32 + i;
    xs[i][tid] = x[((size_t)t * B_SZ + b) * CIN + tid];
  }
  __syncthreads();
  int tx = tid & 63, ty = tid >> 6;
  float acc[8][4];
#pragma unroll
  for (int rr = 0; rr < 8; rr++){ acc[rr][0] = 0.f; acc[rr][1] = 0.f; acc[rr][2] = 0.f; acc[rr][3] = 0.f; }
  gemm_inner(xs, wT, tx, ty, acc);
  float4 bb = *(const float4*)(bias + tx * 4);
#pragma unroll
  for (int rr = 0; rr < 8; rr++){
    int t = tt * 32 + ty * 8 + rr;
    float4 o = make_float4(acc[rr][0] + bb.x, acc[rr][1] + bb.y, acc[rr][2] + bb.z, acc[rr][3] + bb.w);
    *(float4*)(v + ((size_t)b * T_SZ + t) * CIN + tx * 4) = o;
  }
}

// ---------------- scatter: accumulate centers_out numerator/denominator ----------------
__global__ __launch_bounds__(256, 4) void k_scatter(
    const float* __restrict__ v, const u8* __restrict__ selm, const float2* __restrict__ selw,
    float* __restrict__ gacc){
  int bh = blockIdx.x >> 3, chunk = blockIdx.x & 7;
  int b = bh >> 3, h = bh & 7;
  __shared__ float am[16][36];
  for (int i = threadIdx.x; i < 16 * 36; i += 256) ((float*)am)[i] = 0.f;
  __syncthreads();
  for (int rnd = 0; rnd < 2; rnd++){
    int t = chunk * 512 + rnd * 256 + threadIdx.x;
    size_t so = (size_t)bh * T_SZ + t;
    int m1 = selm[so * 2], m2 = selm[so * 2 + 1];
    float2 w = selw[so];
    const float* vr = v + ((size_t)b * T_SZ + t) * CIN + h * 32;
#pragma unroll
    for (int d = 0; d < 32; d += 4){
      float4 vv = *(const float4*)(vr + d);
      atomicAdd(&am[m1][d],     w.x * vv.x); atomicAdd(&am[m1][d + 1], w.x * vv.y);
      atomicAdd(&am[m1][d + 2], w.x * vv.z); atomicAdd(&am[m1][d + 3], w.x * vv.w);
      atomicAdd(&am[m2][d],     w.y * vv.x); atomicAdd(&am[m2][d + 1], w.y * vv.y);
      atomicAdd(&am[m2][d + 2], w.y * vv.z); atomicAdd(&am[m2][d + 3], w.y * vv.w);
    }
    atomicAdd(&am[m1][32], w.x);
    atomicAdd(&am[m2][32], w.y);
  }
  __syncthreads();
  for (int i = threadIdx.x; i < 16 * 33; i += 256){
    int m = i / 33, dd = i % 33;
    atomicAdd(&gacc[(size_t)bh * 528 + i], am[m][dd]);
  }
}

// ---------------- centers_out finalize ----------------
__global__ void k_cfinal(const float* __restrict__ gacc, const float* __restrict__ vc,
                         float* __restrict__ cout){
  int id = blockIdx.x * 256 + threadIdx.x;  // 65536 cells
  int bh = id >> 9, rem = id & 511, m = rem >> 5;
  cout[id] = (gacc[(size_t)bh * 528 + m * 33 + (rem & 31)] + vc[id])
           / (gacc[(size_t)bh * 528 + m * 33 + 32] + 1.0f);
}

// ---------------- fused out_tok build + proj GEMM ----------------
__global__ __launch_bounds__(256, 3) void k_proj(
    const float* __restrict__ cout, const u8* __restrict__ selm, const float2* __restrict__ selw,
    const float* __restrict__ pwT, const float* __restrict__ pb, float* __restrict__ out){
  int b = blockIdx.x >> 7, tt = blockIdx.x & 127;
  __shared__ float xs[32][260];  // out_tok tile
  __shared__ float cs[8][516];   // centers_out for this b
  int tid = threadIdx.x;
  for (int k = 0; k < 16; k++){
    int i = k * 256 + tid;
    cs[i >> 9][i & 511] = cout[(size_t)b * 4096 + i];
  }
  __syncthreads();
  int r = tid >> 3, h = tid & 7;
  int t0 = tt * 32 + r;
  size_t so = (size_t)(b * N_H + h) * T_SZ + t0;
  int m1 = selm[so * 2], m2 = selm[so * 2 + 1];
  float2 w = selw[so];
#pragma unroll
  for (int d = 0; d < 32; d += 4){
    float4 c1 = *(const float4*)&cs[h][m1 * 32 + d];
    float4 c2 = *(const float4*)&cs[h][m2 * 32 + d];
    float4 o = make_float4(w.x * c1.x + w.y * c2.x, w.x * c1.y + w.y * c2.y,
                           w.x * c1.z + w.y * c2.z, w.x * c1.w + w.y * c2.w);
    *(float4*)&xs[r][h * 32 + d] = o;
  }
  __syncthreads();
  int tx = tid & 63, ty = tid >> 6;
  float acc[8][4];
#pragma unroll
  for (int rr = 0; rr < 8; rr++){ acc[rr][0] = 0.f; acc[rr][1] = 0.f; acc[rr][2] = 0.f; acc[rr][3] = 0.f; }
  gemm_inner(xs, pwT, tx, ty, acc);
  float4 bb = *(const float4*)(pb + tx * 4);
#pragma unroll
  for (int rr = 0; rr < 8; rr++){
    int t = tt * 32 + ty * 8 + rr;
    float4 o = make_float4(acc[rr][0] + bb.x, acc[rr][1] + bb.y, acc[rr][2] + bb.z, acc[rr][3] + bb.w);
    *(float4*)(out + ((size_t)t * B_SZ + b) * CIN + tx * 4) = o;
  }
}

extern "C" void kernel_launch(void* const* d_in, const int* in_sizes, int n_in,
                              void* d_out, int out_size, void* d_ws, size_t ws_size,
                              hipStream_t stream) {
  const float* x   = (const float*)d_in[0];
  const float* f_w = (const float*)d_in[1];
  const float* f_b = (const float*)d_in[2];
  const float* v_w = (const float*)d_in[3];
  const float* v_b = (const float*)d_in[4];
  const float* p_w = (const float*)d_in[5];
  const float* p_b = (const float*)d_in[6];
  const float* s_a = (const float*)d_in[7];
  const float* s_b = (const float*)d_in[8];
  float* out = (float*)d_out;
  char* ws = (char*)d_ws;

  float*  fwT  = (float*)(ws + O_FWT);
  float*  vwT  = (float*)(ws + O_VWT);
  float*  pwT  = (float*)(ws + O_PWT);
  double* px   = (double*)(ws + O_PX);
  double* c64  = (double*)(ws + O_C64);
  float*  c32  = (float*)(ws + O_C32);
  float*  vc   = (float*)(ws + O_VC);
  float*  cout = (float*)(ws + O_COUT);
  float*  gacc = (float*)(ws + O_GACC);
  int*    cnt  = (int*)(ws + O_CNT);
  unsigned int* list = (unsigned int*)(ws + O_LIST);
  u8*     selm = (u8*)(ws + O_SELM);
  float2* selw = (float2*)(ws + O_SELW);
  float*  v    = (float*)(ws + O_V);

  hipMemsetAsync(ws + O_GACC, 0, O_LIST - O_GACC, stream);
  k_transpose<<<768, 256, 0, stream>>>(f_w, v_w, p_w, fwT, vwT, pwT);
  k_pool<<<256, 256, 0, stream>>>(x, px);
  k_centers<<<256, 256, 0, stream>>>(px, fwT, vwT, f_b, v_b, c64, c32, vc);
  k_qsim<<<2048, 256, 0, stream>>>(x, fwT, f_b, c32, s_a, s_b, selm, selw, cnt, list);
  k_vgemm<<<2048, 256, 0, stream>>>(x, vwT, v_b, v);
  k_rescue<<<512, 128, 0, stream>>>(x, f_w, f_b, c64, s_a, s_b, cnt, list, selm, selw);
  k_scatter<<<1024, 256, 0, stream>>>(v, selm, selw, gacc);
  k_cfinal<<<256, 256, 0, stream>>>(gacc, vc, cout);
  k_proj<<<2048, 256, 0, stream>>>(cout, selm, selw, pwT, p_b, out);
}

// Round 2
// 683.664 us; speedup vs baseline: 1.3731x; 1.3731x over previous
//
#include <hip/hip_runtime.h>
#include <math.h>

#define T_SZ 4096
#define B_SZ 16
#define CIN 256
#define N_H 8
#define D_H 32
#define M_C 16
#define BH_SZ 128
#define TAU 5e-5f
#define RCAP (1<<21)

typedef unsigned char u8;

// ---- workspace layout (bytes) ----
#define O_FWT   0                    // float[256*256] f_w transposed [c][j]
#define O_VWT   262144               // float[256*256]
#define O_PWT   524288               // float[256*256]
#define O_PX    786432               // double[B*16*256] pooled x (mean)
#define O_C64   1310720              // double[B*H*16*32] normalized centers
#define O_C32   1835008              // float  same
#define O_VC    2097152              // float[B*H*16*32] value centers
#define O_COUT  2359296              // float[B*H*16*32] centers_out
#define O_GACC  2621440              // float[128*16*33] scatter accum
#define O_CNT   2891776              // int rescue counter
#define O_LIST  2892032              // uint[RCAP]
#define O_SELM  11280640             // u8[128*4096*2]
#define O_SELW  12329216             // float2[128*4096]
#define O_V     16523520             // float[B*T*256]
// end = 83632384 (~84 MB)

// ---------------- weight transpose ----------------
__global__ void k_transpose(const float* __restrict__ fw, const float* __restrict__ vw,
                            const float* __restrict__ pw, float* __restrict__ fwT,
                            float* __restrict__ vwT, float* __restrict__ pwT){
  int id = blockIdx.x * 256 + threadIdx.x;
  int mat = id >> 16; int rem = id & 65535;
  int j = rem >> 8, c = rem & 255;
  const float* src = (mat == 0) ? fw : ((mat == 1) ? vw : pw);
  float* dst = (mat == 0) ? fwT : ((mat == 1) ? vwT : pwT);
  dst[c * 256 + j] = src[j * 256 + c];
}

// ---------------- fp64 spatial pooling of x ----------------
__global__ void k_pool(const float* __restrict__ x, double* __restrict__ px){
  int b = blockIdx.x >> 4, m = blockIdx.x & 15;
  int pr = m >> 2, pc = m & 3;
  int c = threadIdx.x;
  double s = 0.0;
  for (int i = 0; i < 16; i++){
    int t0 = (pr * 16 + i) * 64 + pc * 16;
    const float* xr = x + ((size_t)t0 * B_SZ + b) * CIN + c;
    for (int jj = 0; jj < 16; jj++)
      s += (double)xr[(size_t)jj * B_SZ * CIN];
  }
  px[(size_t)(b * 16 + m) * 256 + c] = s * (1.0 / 256.0);
}

// ---------------- fp64 centers + value centers ----------------
__global__ void k_centers(const double* __restrict__ px, const float* __restrict__ fwT,
                          const float* __restrict__ vwT, const float* __restrict__ fb,
                          const float* __restrict__ vb, double* __restrict__ c64,
                          float* __restrict__ c32, float* __restrict__ vc){
  int b = blockIdx.x >> 4, m = blockIdx.x & 15;
  int j = threadIdx.x;
  const double* pxr = px + (size_t)(b * 16 + m) * 256;
  double cq = (double)fb[j], cv = (double)vb[j];
  for (int c = 0; c < 256; c++){
    double p = pxr[c];
    cq += p * (double)fwT[c * 256 + j];
    cv += p * (double)vwT[c * 256 + j];
  }
  __shared__ double sq[256];
  __shared__ double snm[8];
  sq[j] = cq * cq;
  __syncthreads();
  int h = j >> 5, d = j & 31;
  if ((j & 31) == 0){
    double ts = 0.0;
    for (int dd = 0; dd < 32; dd++) ts += sq[h * 32 + dd];
    snm[h] = fmax(sqrt(ts), 1e-12);
  }
  __syncthreads();
  double nm = snm[h];
  size_t o = ((size_t)(b * N_H + h) * M_C + m) * D_H + d;
  double ch = cq / nm;
  c64[o] = ch; c32[o] = (float)ch; vc[o] = (float)cv;
}

// ---------------- shared register-blocked GEMM inner (32 rows x 256 cols, K=256) ----------------
__device__ __forceinline__ void gemm_inner(const float (*xs)[260], const float* __restrict__ wT,
                                           int tx, int ty, float acc[8][4]){
  for (int c = 0; c < 256; c += 4){
    const float4 w0 = *(const float4*)(wT + (size_t)(c + 0) * 256 + tx * 4);
    const float4 w1 = *(const float4*)(wT + (size_t)(c + 1) * 256 + tx * 4);
    const float4 w2 = *(const float4*)(wT + (size_t)(c + 2) * 256 + tx * 4);
    const float4 w3 = *(const float4*)(wT + (size_t)(c + 3) * 256 + tx * 4);
#pragma unroll
    for (int rr = 0; rr < 8; rr++){
      const float4 xv = *(const float4*)&xs[ty * 8 + rr][c];
      acc[rr][0] = fmaf(xv.x, w0.x, fmaf(xv.y, w1.x, fmaf(xv.z, w2.x, fmaf(xv.w, w3.x, acc[rr][0]))));
      acc[rr][1] = fmaf(xv.x, w0.y, fmaf(xv.y, w1.y, fmaf(xv.z, w2.y, fmaf(xv.w, w3.y, acc[rr][1]))));
      acc[rr][2] = fmaf(xv.x, w0.z, fmaf(xv.y, w1.z, fmaf(xv.z, w2.z, fmaf(xv.w, w3.z, acc[rr][2]))));
      acc[rr][3] = fmaf(xv.x, w0.w, fmaf(xv.y, w1.w, fmaf(xv.z, w2.w, fmaf(xv.w, w3.w, acc[rr][3]))));
    }
  }
}

// ---------------- q GEMM + similarity + top-2 ----------------
__global__ __launch_bounds__(256, 3) void k_qsim(
    const float* __restrict__ x, const float* __restrict__ fwT, const float* __restrict__ fb,
    const float* __restrict__ c32, const float* __restrict__ salpha, const float* __restrict__ sbeta,
    u8* __restrict__ selm, float2* __restrict__ selw, int* __restrict__ cnt,
    unsigned int* __restrict__ list){
  int b = blockIdx.x >> 7, tt = blockIdx.x & 127;
  __shared__ float xs[32][260];   // x tile, becomes q tile
  __shared__ float cs[8][516];    // normalized centers for this b
  int tid = threadIdx.x;
  for (int k = 0; k < 16; k++){
    int i = k * 256 + tid;
    cs[i >> 9][i & 511] = c32[(size_t)b * 4096 + i];
  }
  for (int i = 0; i < 32; i++){
    int t = tt * 32 + i;
    xs[i][tid] = x[((size_t)t * B_SZ + b) * CIN + tid];
  }
  __syncthreads();
  int tx = tid & 63, ty = tid >> 6;
  float acc[8][4];
#pragma unroll
  for (int rr = 0; rr < 8; rr++){ acc[rr][0] = 0.f; acc[rr][1] = 0.f; acc[rr][2] = 0.f; acc[rr][3] = 0.f; }
  gemm_inner(xs, fwT, tx, ty, acc);
  float4 bb = *(const float4*)(fb + tx * 4);
  __syncthreads();  // all xs reads done, safe to overwrite with q
#pragma unroll
  for (int rr = 0; rr < 8; rr++){
    float4 qv = make_float4(acc[rr][0] + bb.x, acc[rr][1] + bb.y, acc[rr][2] + bb.z, acc[rr][3] + bb.w);
    *(float4*)&xs[ty * 8 + rr][tx * 4] = qv;
  }
  __syncthreads();
  // phase 2: one thread per (token, head)
  int r = tid >> 3, h = tid & 7;
  int t = tt * 32 + r;
  float q[32];
  float ss = 0.f;
#pragma unroll
  for (int d = 0; d < 32; d += 4){
    float4 qv = *(const float4*)&xs[r][h * 32 + d];
    q[d] = qv.x; q[d + 1] = qv.y; q[d + 2] = qv.z; q[d + 3] = qv.w;
    ss += qv.x * qv.x + qv.y * qv.y + qv.z * qv.z + qv.w * qv.w;
  }
  float inv = 1.f / fmaxf(sqrtf(ss), 1e-12f);
  float alpha = salpha[0], beta = sbeta[0];
  float s1 = -1e30f, s2 = -1e30f, s3 = -1e30f; int i1 = 0, i2 = 0;
#pragma unroll
  for (int m = 0; m < 16; m++){
    float dot = 0.f;
#pragma unroll
    for (int d = 0; d < 32; d += 4){
      float4 cv = *(const float4*)&cs[h][m * 32 + d];
      dot = fmaf(q[d], cv.x, fmaf(q[d + 1], cv.y, fmaf(q[d + 2], cv.z, fmaf(q[d + 3], cv.w, dot))));
    }
    float z = beta + alpha * (dot * inv);
    float s = 1.f / (1.f + expf(-z));
    if (s > s1){ s3 = s2; s2 = s1; i2 = i1; s1 = s; i1 = m; }
    else if (s > s2){ s3 = s2; s2 = s; i2 = m; }
    else if (s > s3){ s3 = s; }
  }
  if (s2 - s3 < TAU){
    int idx = atomicAdd(cnt, 1);
    if (idx < RCAP) list[idx] = (((unsigned)(b * N_H + h)) << 12) | (unsigned)t;
  }
  float r1 = s1 * s1, r2 = s2 * s2;
  float den = r1 + r2 + 1e-6f;
  size_t so = (size_t)(b * N_H + h) * T_SZ + t;
  selm[so * 2] = (u8)i1; selm[so * 2 + 1] = (u8)i2;
  selw[so] = make_float2(r1 / den, r2 / den);
}

// ---------------- fp64 rescue for near-tie tokens: ONE WAVE PER TOKEN ----------------
__global__ __launch_bounds__(256, 4) void k_rescue(
    const float* __restrict__ x, const float* __restrict__ fw, const float* __restrict__ fb,
    const double* __restrict__ c64, const float* __restrict__ salpha, const float* __restrict__ sbeta,
    const int* __restrict__ cnt, const unsigned int* __restrict__ list,
    u8* __restrict__ selm, float2* __restrict__ selw){
  int n = *cnt; if (n > RCAP) n = RCAP;
  int lane = threadIdx.x & 63;
  int wid = (blockIdx.x * 256 + threadIdx.x) >> 6;
  int nw = gridDim.x * 4;
  double alpha = (double)salpha[0], beta = (double)sbeta[0];
  for (int i = wid; i < n; i += nw){
    unsigned e = list[i];
    int t = e & 4095; int bh = e >> 12; int b = bh >> 3, h = bh & 7;
    int d = lane & 31, half = lane >> 5;
    const float* xh = x + ((size_t)t * B_SZ + b) * CIN + half * 128;
    const float* wr = fw + (size_t)(h * 32 + d) * CIN + half * 128;
    double a0 = 0, a1 = 0, a2 = 0, a3 = 0;
#pragma unroll 4
    for (int c = 0; c < 128; c += 4){
      float4 xv = *(const float4*)(xh + c);
      float4 wv = *(const float4*)(wr + c);
      a0 += (double)xv.x * (double)wv.x;
      a1 += (double)xv.y * (double)wv.y;
      a2 += (double)xv.z * (double)wv.z;
      a3 += (double)xv.w * (double)wv.w;
    }
    double qd = (a0 + a1) + (a2 + a3);
    qd += __shfl_down(qd, 32);              // lanes 0..31 now hold full dot
    if (lane < 32) qd += (double)fb[h * 32 + d];
    else qd = 0.0;
    double ss = qd * qd;
#pragma unroll
    for (int off = 32; off; off >>= 1) ss += __shfl_xor(ss, off);
    double inv = 1.0 / fmax(sqrt(ss), 1e-12);
    // sims: lane m = lane&15 (replicated) computes sim for center m
    const double* cb = c64 + (size_t)bh * (M_C * D_H);
    int m = lane & 15;
    double dot = 0.0;
#pragma unroll
    for (int dd = 0; dd < 32; dd++){
      double qv = __shfl(qd, dd);
      dot += qv * cb[m * 32 + dd];
    }
    double z = beta + alpha * (dot * inv);
    double s = 1.0 / (1.0 + exp(-z));
    // gather the 16 sims to all lanes; identical top-2 on every lane
    double s1 = -1e300, s2 = -1e300; int i1 = 0, i2 = 0;
#pragma unroll
    for (int mm = 0; mm < 16; mm++){
      double sv = __shfl(s, mm);
      if (sv > s1){ s2 = s1; i2 = i1; s1 = sv; i1 = mm; }
      else if (sv > s2){ s2 = sv; i2 = mm; }
    }
    if (lane == 0){
      double r1 = s1 * s1, r2 = s2 * s2, den = r1 + r2 + 1e-6;
      size_t so = (size_t)bh * T_SZ + t;
      selm[so * 2] = (u8)i1; selm[so * 2 + 1] = (u8)i2;
      selw[so] = make_float2((float)(r1 / den), (float)(r2 / den));
    }
  }
}

// ---------------- v GEMM ----------------
__global__ __launch_bounds__(256, 4) void k_vgemm(
    const float* __restrict__ x, const float* __restrict__ wT, const float* __restrict__ bias,
    float* __restrict__ v){
  int b = blockIdx.x >> 7, tt = blockIdx.x & 127;
  __shared__ float xs[32][260];
  int tid = threadIdx.x;
  for (int i = 0; i < 32; i++){
    int t = tt * 32 + i;
    xs[i][tid] = x[((size_t)t * B_SZ + b) * CIN + tid];
  }
  __syncthreads();
  int tx = tid & 63, ty = tid >> 6;
  float acc[8][4];
#pragma unroll
  for (int rr = 0; rr < 8; rr++){ acc[rr][0] = 0.f; acc[rr][1] = 0.f; acc[rr][2] = 0.f; acc[rr][3] = 0.f; }
  gemm_inner(xs, wT, tx, ty, acc);
  float4 bb = *(const float4*)(bias + tx * 4);
#pragma unroll
  for (int rr = 0; rr < 8; rr++){
    int t = tt * 32 + ty * 8 + rr;
    float4 o = make_float4(acc[rr][0] + bb.x, acc[rr][1] + bb.y, acc[rr][2] + bb.z, acc[rr][3] + bb.w);
    *(float4*)(v + ((size_t)b * T_SZ + t) * CIN + tx * 4) = o;
  }
}

// ---------------- scatter: accumulate centers_out numerator/denominator ----------------
__global__ __launch_bounds__(256, 4) void k_scatter(
    const float* __restrict__ v, const u8* __restrict__ selm, const float2* __restrict__ selw,
    float* __restrict__ gacc){
  int bh = blockIdx.x >> 3, chunk = blockIdx.x & 7;
  int b = bh >> 3, h = bh & 7;
  __shared__ float am[16][36];
  for (int i = threadIdx.x; i < 16 * 36; i += 256) ((float*)am)[i] = 0.f;
  __syncthreads();
  for (int rnd = 0; rnd < 2; rnd++){
    int t = chunk * 512 + rnd * 256 + threadIdx.x;
    size_t so = (size_t)bh * T_SZ + t;
    int m1 = selm[so * 2], m2 = selm[so * 2 + 1];
    float2 w = selw[so];
    const float* vr = v + ((size_t)b * T_SZ + t) * CIN + h * 32;
#pragma unroll
    for (int d = 0; d < 32; d += 4){
      float4 vv = *(const float4*)(vr + d);
      atomicAdd(&am[m1][d],     w.x * vv.x); atomicAdd(&am[m1][d + 1], w.x * vv.y);
      atomicAdd(&am[m1][d + 2], w.x * vv.z); atomicAdd(&am[m1][d + 3], w.x * vv.w);
      atomicAdd(&am[m2][d],     w.y * vv.x); atomicAdd(&am[m2][d + 1], w.y * vv.y);
      atomicAdd(&am[m2][d + 2], w.y * vv.z); atomicAdd(&am[m2][d + 3], w.y * vv.w);
    }
    atomicAdd(&am[m1][32], w.x);
    atomicAdd(&am[m2][32], w.y);
  }
  __syncthreads();
  for (int i = threadIdx.x; i < 16 * 33; i += 256){
    int m = i / 33, dd = i % 33;
    atomicAdd(&gacc[(size_t)bh * 528 + i], am[m][dd]);
  }
}

// ---------------- centers_out finalize ----------------
__global__ void k_cfinal(const float* __restrict__ gacc, const float* __restrict__ vc,
                         float* __restrict__ cout){
  int id = blockIdx.x * 256 + threadIdx.x;  // 65536 cells
  int bh = id >> 9, rem = id & 511, m = rem >> 5;
  cout[id] = (gacc[(size_t)bh * 528 + m * 33 + (rem & 31)] + vc[id])
           / (gacc[(size_t)bh * 528 + m * 33 + 32] + 1.0f);
}

// ---------------- fused out_tok build + proj GEMM ----------------
__global__ __launch_bounds__(256, 3) void k_proj(
    const float* __restrict__ cout, const u8* __restrict__ selm, const float2* __restrict__ selw,
    const float* __restrict__ pwT, const float* __restrict__ pb, float* __restrict__ out){
  int b = blockIdx.x >> 7, tt = blockIdx.x & 127;
  __shared__ float xs[32][260];  // out_tok tile
  __shared__ float cs[8][516];   // centers_out for this b
  int tid = threadIdx.x;
  for (int k = 0; k < 16; k++){
    int i = k * 256 + tid;
    cs[i >> 9][i & 511] = cout[(size_t)b * 4096 + i];
  }
  __syncthreads();
  int r = tid >> 3, h = tid & 7;
  int t0 = tt * 32 + r;
  size_t so = (size_t)(b * N_H + h) * T_SZ + t0;
  int m1 = selm[so * 2], m2 = selm[so * 2 + 1];
  float2 w = selw[so];
#pragma unroll
  for (int d = 0; d < 32; d += 4){
    float4 c1 = *(const float4*)&cs[h][m1 * 32 + d];
    float4 c2 = *(const float4*)&cs[h][m2 * 32 + d];
    float4 o = make_float4(w.x * c1.x + w.y * c2.x, w.x * c1.y + w.y * c2.y,
                           w.x * c1.z + w.y * c2.z, w.x * c1.w + w.y * c2.w);
    *(float4*)&xs[r][h * 32 + d] = o;
  }
  __syncthreads();
  int tx = tid & 63, ty = tid >> 6;
  float acc[8][4];
#pragma unroll
  for (int rr = 0; rr < 8; rr++){ acc[rr][0] = 0.f; acc[rr][1] = 0.f; acc[rr][2] = 0.f; acc[rr][3] = 0.f; }
  gemm_inner(xs, pwT, tx, ty, acc);
  float4 bb = *(const float4*)(pb + tx * 4);
#pragma unroll
  for (int rr = 0; rr < 8; rr++){
    int t = tt * 32 + ty * 8 + rr;
    float4 o = make_float4(acc[rr][0] + bb.x, acc[rr][1] + bb.y, acc[rr][2] + bb.z, acc[rr][3] + bb.w);
    *(float4*)(out + ((size_t)t * B_SZ + b) * CIN + tx * 4) = o;
  }
}

extern "C" void kernel_launch(void* const* d_in, const int* in_sizes, int n_in,
                              void* d_out, int out_size, void* d_ws, size_t ws_size,
                              hipStream_t stream) {
  const float* x   = (const float*)d_in[0];
  const float* f_w = (const float*)d_in[1];
  const float* f_b = (const float*)d_in[2];
  const float* v_w = (const float*)d_in[3];
  const float* v_b = (const float*)d_in[4];
  const float* p_w = (const float*)d_in[5];
  const float* p_b = (const float*)d_in[6];
  const float* s_a = (const float*)d_in[7];
  const float* s_b = (const float*)d_in[8];
  float* out = (float*)d_out;
  char* ws = (char*)d_ws;

  float*  fwT  = (float*)(ws + O_FWT);
  float*  vwT  = (float*)(ws + O_VWT);
  float*  pwT  = (float*)(ws + O_PWT);
  double* px   = (double*)(ws + O_PX);
  double* c64  = (double*)(ws + O_C64);
  float*  c32  = (float*)(ws + O_C32);
  float*  vc   = (float*)(ws + O_VC);
  float*  cout = (float*)(ws + O_COUT);
  float*  gacc = (float*)(ws + O_GACC);
  int*    cnt  = (int*)(ws + O_CNT);
  unsigned int* list = (unsigned int*)(ws + O_LIST);
  u8*     selm = (u8*)(ws + O_SELM);
  float2* selw = (float2*)(ws + O_SELW);
  float*  v    = (float*)(ws + O_V);

  hipMemsetAsync(ws + O_GACC, 0, O_LIST - O_GACC, stream);
  k_transpose<<<768, 256, 0, stream>>>(f_w, v_w, p_w, fwT, vwT, pwT);
  k_pool<<<256, 256, 0, stream>>>(x, px);
  k_centers<<<256, 256, 0, stream>>>(px, fwT, vwT, f_b, v_b, c64, c32, vc);
  k_qsim<<<2048, 256, 0, stream>>>(x, fwT, f_b, c32, s_a, s_b, selm, selw, cnt, list);
  k_vgemm<<<2048, 256, 0, stream>>>(x, vwT, v_b, v);
  k_rescue<<<256, 256, 0, stream>>>(x, f_w, f_b, c64, s_a, s_b, cnt, list, selm, selw);
  k_scatter<<<1024, 256, 0, stream>>>(v, selm, selw, gacc);
  k_cfinal<<<256, 256, 0, stream>>>(gacc, vc, cout);
  k_proj<<<2048, 256, 0, stream>>>(cout, selm, selw, pwT, p_b, out);
}

// Round 3
// 550.194 us; speedup vs baseline: 1.7062x; 1.2426x over previous
//
#include <hip/hip_runtime.h>
#include <math.h>

#define T_SZ 4096
#define B_SZ 16
#define CIN 256
#define N_H 8
#define D_H 32
#define M_C 16
#define TAU 5e-5f
#define RCAP (1<<19)

typedef unsigned char u8;

// ---- workspace layout (bytes) ----
#define O_FWT   0                    // float[256*256] f_w transposed [c][j]
#define O_VWT   262144               // float[256*256]
#define O_PWT   524288               // float[256*256]
#define O_PX    786432               // double[B*16*256] pooled x (mean)
#define O_C64   1310720              // double[B*H*16*32] normalized centers
#define O_C32   1835008              // float  same
#define O_VC    2097152              // float[B*H*16*32] value centers
#define O_COUT  2359296              // float[B*H*16*32] centers_out
#define O_GPART 2621440              // float[128*8*528] scatter partials (no memset: fully written)
#define O_CNT   4784128              // int rescue counter
#define O_LIST  4784384              // uint[RCAP]  (RCAP == max flaggable tokens)
#define O_SELM  6881536              // u8[128*4096*2]
#define O_SELW  7930112              // float2[128*4096]
#define O_V     12124416             // float[B*T*256]
// end = 79233280 (~76 MB)

// ---------------- weight transpose ----------------
__global__ void k_transpose(const float* __restrict__ fw, const float* __restrict__ vw,
                            const float* __restrict__ pw, float* __restrict__ fwT,
                            float* __restrict__ vwT, float* __restrict__ pwT){
  int id = blockIdx.x * 256 + threadIdx.x;
  int mat = id >> 16; int rem = id & 65535;
  int j = rem >> 8, c = rem & 255;
  const float* src = (mat == 0) ? fw : ((mat == 1) ? vw : pw);
  float* dst = (mat == 0) ? fwT : ((mat == 1) ? vwT : pwT);
  dst[c * 256 + j] = src[j * 256 + c];
}

// ---------------- fp64 spatial pooling of x ----------------
__global__ void k_pool(const float* __restrict__ x, double* __restrict__ px){
  int b = blockIdx.x >> 4, m = blockIdx.x & 15;
  int pr = m >> 2, pc = m & 3;
  int c = threadIdx.x;
  double s = 0.0;
  for (int i = 0; i < 16; i++){
    int t0 = (pr * 16 + i) * 64 + pc * 16;
    const float* xr = x + ((size_t)t0 * B_SZ + b) * CIN + c;
    for (int jj = 0; jj < 16; jj++)
      s += (double)xr[(size_t)jj * B_SZ * CIN];
  }
  px[(size_t)(b * 16 + m) * 256 + c] = s * (1.0 / 256.0);
}

// ---------------- fp64 centers + value centers ----------------
__global__ void k_centers(const double* __restrict__ px, const float* __restrict__ fwT,
                          const float* __restrict__ vwT, const float* __restrict__ fb,
                          const float* __restrict__ vb, double* __restrict__ c64,
                          float* __restrict__ c32, float* __restrict__ vc){
  int b = blockIdx.x >> 4, m = blockIdx.x & 15;
  int j = threadIdx.x;
  const double* pxr = px + (size_t)(b * 16 + m) * 256;
  double cq = (double)fb[j], cv = (double)vb[j];
  for (int c = 0; c < 256; c++){
    double p = pxr[c];
    cq += p * (double)fwT[c * 256 + j];
    cv += p * (double)vwT[c * 256 + j];
  }
  __shared__ double sq[256];
  __shared__ double snm[8];
  sq[j] = cq * cq;
  __syncthreads();
  int h = j >> 5, d = j & 31;
  if ((j & 31) == 0){
    double ts = 0.0;
    for (int dd = 0; dd < 32; dd++) ts += sq[h * 32 + dd];
    snm[h] = fmax(sqrt(ts), 1e-12);
  }
  __syncthreads();
  double nm = snm[h];
  size_t o = ((size_t)(b * N_H + h) * M_C + m) * D_H + d;
  double ch = cq / nm;
  c64[o] = ch; c32[o] = (float)ch; vc[o] = (float)cv;
}

// ---------------- shared register-blocked GEMM inner (32 rows x 256 cols, K=256) ----------------
__device__ __forceinline__ void gemm_inner(const float (*xs)[260], const float* __restrict__ wT,
                                           int tx, int ty, float acc[8][4]){
  for (int c = 0; c < 256; c += 4){
    const float4 w0 = *(const float4*)(wT + (size_t)(c + 0) * 256 + tx * 4);
    const float4 w1 = *(const float4*)(wT + (size_t)(c + 1) * 256 + tx * 4);
    const float4 w2 = *(const float4*)(wT + (size_t)(c + 2) * 256 + tx * 4);
    const float4 w3 = *(const float4*)(wT + (size_t)(c + 3) * 256 + tx * 4);
#pragma unroll
    for (int rr = 0; rr < 8; rr++){
      const float4 xv = *(const float4*)&xs[ty * 8 + rr][c];
      acc[rr][0] = fmaf(xv.x, w0.x, fmaf(xv.y, w1.x, fmaf(xv.z, w2.x, fmaf(xv.w, w3.x, acc[rr][0]))));
      acc[rr][1] = fmaf(xv.x, w0.y, fmaf(xv.y, w1.y, fmaf(xv.z, w2.y, fmaf(xv.w, w3.y, acc[rr][1]))));
      acc[rr][2] = fmaf(xv.x, w0.z, fmaf(xv.y, w1.z, fmaf(xv.z, w2.z, fmaf(xv.w, w3.z, acc[rr][2]))));
      acc[rr][3] = fmaf(xv.x, w0.w, fmaf(xv.y, w1.w, fmaf(xv.z, w2.w, fmaf(xv.w, w3.w, acc[rr][3]))));
    }
  }
}

// ---------------- q GEMM + similarity + top-2 ----------------
__global__ __launch_bounds__(256, 3) void k_qsim(
    const float* __restrict__ x, const float* __restrict__ fwT, const float* __restrict__ fb,
    const float* __restrict__ c32, const float* __restrict__ salpha, const float* __restrict__ sbeta,
    u8* __restrict__ selm, float2* __restrict__ selw, int* __restrict__ cnt,
    unsigned int* __restrict__ list){
  int b = blockIdx.x >> 7, tt = blockIdx.x & 127;
  __shared__ float xs[32][260];   // x tile, becomes q tile
  __shared__ float cs[8][516];    // normalized centers for this b
  int tid = threadIdx.x;
  for (int k = 0; k < 16; k++){
    int i = k * 256 + tid;
    cs[i >> 9][i & 511] = c32[(size_t)b * 4096 + i];
  }
  for (int i = 0; i < 32; i++){
    int t = tt * 32 + i;
    xs[i][tid] = x[((size_t)t * B_SZ + b) * CIN + tid];
  }
  __syncthreads();
  int tx = tid & 63, ty = tid >> 6;
  float acc[8][4];
#pragma unroll
  for (int rr = 0; rr < 8; rr++){ acc[rr][0] = 0.f; acc[rr][1] = 0.f; acc[rr][2] = 0.f; acc[rr][3] = 0.f; }
  gemm_inner(xs, fwT, tx, ty, acc);
  float4 bb = *(const float4*)(fb + tx * 4);
  __syncthreads();  // all xs reads done, safe to overwrite with q
#pragma unroll
  for (int rr = 0; rr < 8; rr++){
    float4 qv = make_float4(acc[rr][0] + bb.x, acc[rr][1] + bb.y, acc[rr][2] + bb.z, acc[rr][3] + bb.w);
    *(float4*)&xs[ty * 8 + rr][tx * 4] = qv;
  }
  __syncthreads();
  // phase 2: one thread per (token, head)
  int r = tid >> 3, h = tid & 7;
  int t = tt * 32 + r;
  float q[32];
  float ss = 0.f;
#pragma unroll
  for (int d = 0; d < 32; d += 4){
    float4 qv = *(const float4*)&xs[r][h * 32 + d];
    q[d] = qv.x; q[d + 1] = qv.y; q[d + 2] = qv.z; q[d + 3] = qv.w;
    ss += qv.x * qv.x + qv.y * qv.y + qv.z * qv.z + qv.w * qv.w;
  }
  float inv = 1.f / fmaxf(sqrtf(ss), 1e-12f);
  float alpha = salpha[0], beta = sbeta[0];
  float s1 = -1e30f, s2 = -1e30f, s3 = -1e30f; int i1 = 0, i2 = 0;
#pragma unroll
  for (int m = 0; m < 16; m++){
    float dot = 0.f;
#pragma unroll
    for (int d = 0; d < 32; d += 4){
      float4 cv = *(const float4*)&cs[h][m * 32 + d];
      dot = fmaf(q[d], cv.x, fmaf(q[d + 1], cv.y, fmaf(q[d + 2], cv.z, fmaf(q[d + 3], cv.w, dot))));
    }
    float z = beta + alpha * (dot * inv);
    float s = 1.f / (1.f + expf(-z));
    if (s > s1){ s3 = s2; s2 = s1; i2 = i1; s1 = s; i1 = m; }
    else if (s > s2){ s3 = s2; s2 = s; i2 = m; }
    else if (s > s3){ s3 = s; }
  }
  if (s2 - s3 < TAU){
    int idx = atomicAdd(cnt, 1);
    if (idx < RCAP) list[idx] = (((unsigned)(b * N_H + h)) << 12) | (unsigned)t;
  }
  float r1 = s1 * s1, r2 = s2 * s2;
  float den = r1 + r2 + 1e-6f;
  size_t so = (size_t)(b * N_H + h) * T_SZ + t;
  selm[so * 2] = (u8)i1; selm[so * 2 + 1] = (u8)i2;
  selw[so] = make_float2(r1 / den, r2 / den);
}

// ---------------- fp64 rescue for near-tie tokens: ONE WAVE PER TOKEN ----------------
__global__ __launch_bounds__(256, 4) void k_rescue(
    const float* __restrict__ x, const float* __restrict__ fw, const float* __restrict__ fb,
    const double* __restrict__ c64, const float* __restrict__ salpha, const float* __restrict__ sbeta,
    const int* __restrict__ cnt, const unsigned int* __restrict__ list,
    u8* __restrict__ selm, float2* __restrict__ selw){
  int n = *cnt; if (n > RCAP) n = RCAP;
  int lane = threadIdx.x & 63;
  int wid = (blockIdx.x * 256 + threadIdx.x) >> 6;
  int nw = gridDim.x * 4;
  double alpha = (double)salpha[0], beta = (double)sbeta[0];
  for (int i = wid; i < n; i += nw){
    unsigned e = list[i];
    int t = e & 4095; int bh = e >> 12; int b = bh >> 3, h = bh & 7;
    int d = lane & 31, half = lane >> 5;
    const float* xh = x + ((size_t)t * B_SZ + b) * CIN + half * 128;
    const float* wr = fw + (size_t)(h * 32 + d) * CIN + half * 128;
    double a0 = 0, a1 = 0, a2 = 0, a3 = 0;
#pragma unroll 4
    for (int c = 0; c < 128; c += 4){
      float4 xv = *(const float4*)(xh + c);
      float4 wv = *(const float4*)(wr + c);
      a0 += (double)xv.x * (double)wv.x;
      a1 += (double)xv.y * (double)wv.y;
      a2 += (double)xv.z * (double)wv.z;
      a3 += (double)xv.w * (double)wv.w;
    }
    double qd = (a0 + a1) + (a2 + a3);
    qd += __shfl_down(qd, 32);              // lanes 0..31 now hold full dot
    if (lane < 32) qd += (double)fb[h * 32 + d];
    else qd = 0.0;
    double ss = qd * qd;
#pragma unroll
    for (int off = 32; off; off >>= 1) ss += __shfl_xor(ss, off);
    double inv = 1.0 / fmax(sqrt(ss), 1e-12);
    const double* cb = c64 + (size_t)bh * (M_C * D_H);
    int m = lane & 15;
    double dot = 0.0;
#pragma unroll
    for (int dd = 0; dd < 32; dd++){
      double qv = __shfl(qd, dd);
      dot += qv * cb[m * 32 + dd];
    }
    double z = beta + alpha * (dot * inv);
    double s = 1.0 / (1.0 + exp(-z));
    double s1 = -1e300, s2 = -1e300; int i1 = 0, i2 = 0;
#pragma unroll
    for (int mm = 0; mm < 16; mm++){
      double sv = __shfl(s, mm);
      if (sv > s1){ s2 = s1; i2 = i1; s1 = sv; i1 = mm; }
      else if (sv > s2){ s2 = sv; i2 = mm; }
    }
    if (lane == 0){
      double r1 = s1 * s1, r2 = s2 * s2, den = r1 + r2 + 1e-6;
      size_t so = (size_t)bh * T_SZ + t;
      selm[so * 2] = (u8)i1; selm[so * 2 + 1] = (u8)i2;
      selw[so] = make_float2((float)(r1 / den), (float)(r2 / den));
    }
  }
}

// ---------------- v GEMM ----------------
__global__ __launch_bounds__(256, 4) void k_vgemm(
    const float* __restrict__ x, const float* __restrict__ wT, const float* __restrict__ bias,
    float* __restrict__ v){
  int b = blockIdx.x >> 7, tt = blockIdx.x & 127;
  __shared__ float xs[32][260];
  int tid = threadIdx.x;
  for (int i = 0; i < 32; i++){
    int t = tt * 32 + i;
    xs[i][tid] = x[((size_t)t * B_SZ + b) * CIN + tid];
  }
  __syncthreads();
  int tx = tid & 63, ty = tid >> 6;
  float acc[8][4];
#pragma unroll
  for (int rr = 0; rr < 8; rr++){ acc[rr][0] = 0.f; acc[rr][1] = 0.f; acc[rr][2] = 0.f; acc[rr][3] = 0.f; }
  gemm_inner(xs, wT, tx, ty, acc);
  float4 bb = *(const float4*)(bias + tx * 4);
#pragma unroll
  for (int rr = 0; rr < 8; rr++){
    int t = tt * 32 + ty * 8 + rr;
    float4 o = make_float4(acc[rr][0] + bb.x, acc[rr][1] + bb.y, acc[rr][2] + bb.z, acc[rr][3] + bb.w);
    *(float4*)(v + ((size_t)b * T_SZ + t) * CIN + tx * 4) = o;
  }
}

// ---------------- scatter: ownership-transposed, NO atomics ----------------
// block = (bh, chunk of 512 tokens); thread owns cells (mA=tid>>5, d=tid&31) and (mA+8, d)
__global__ __launch_bounds__(256, 4) void k_scatter(
    const float* __restrict__ v, const u8* __restrict__ selm, const float2* __restrict__ selw,
    float* __restrict__ gpart){
  int bh = blockIdx.x >> 3, chunk = blockIdx.x & 7;
  int b = bh >> 3, h = bh & 7;
  int tid = threadIdx.x;
  int mA = tid >> 5, mB = mA + 8, d = tid & 31;
  __shared__ uchar2 sm[512];
  __shared__ float2 sw[512];
  for (int i = tid; i < 512; i += 256){
    size_t so = (size_t)bh * T_SZ + chunk * 512 + i;
    sm[i] = make_uchar2(selm[so * 2], selm[so * 2 + 1]);
    sw[i] = selw[so];
  }
  __syncthreads();
  const float* vb = v + ((size_t)b * T_SZ + chunk * 512) * CIN + h * 32 + d;
  float accA = 0.f, accB = 0.f, cntA = 0.f, cntB = 0.f;
#pragma unroll 8
  for (int i = 0; i < 512; i++){
    float vv = vb[(size_t)i * CIN];
    uchar2 mm = sm[i];
    float2 w = sw[i];
    float wA = (mm.x == mA) ? w.x : ((mm.y == mA) ? w.y : 0.f);
    float wB = (mm.x == mB) ? w.x : ((mm.y == mB) ? w.y : 0.f);
    accA = fmaf(wA, vv, accA); cntA += wA;
    accB = fmaf(wB, vv, accB); cntB += wB;
  }
  float* gp = gpart + (size_t)(bh * 8 + chunk) * 528;
  gp[mA * 33 + d] = accA;
  gp[mB * 33 + d] = accB;
  if (d == 0){ gp[mA * 33 + 32] = cntA; gp[mB * 33 + 32] = cntB; }
}

// ---------------- centers_out finalize: reduce 8 chunk partials ----------------
__global__ void k_cfinal(const float* __restrict__ gpart, const float* __restrict__ vc,
                         float* __restrict__ cout){
  int id = blockIdx.x * 256 + threadIdx.x;  // 65536 cells
  int bh = id >> 9, rem = id & 511, m = rem >> 5, d = rem & 31;
  float num = 0.f, den = 0.f;
#pragma unroll
  for (int c = 0; c < 8; c++){
    const float* gp = gpart + (size_t)(bh * 8 + c) * 528 + m * 33;
    num += gp[d];
    den += gp[32];
  }
  cout[id] = (num + vc[id]) / (den + 1.0f);
}

// ---------------- fused out_tok build + proj GEMM ----------------
__global__ __launch_bounds__(256, 3) void k_proj(
    const float* __restrict__ cout, const u8* __restrict__ selm, const float2* __restrict__ selw,
    const float* __restrict__ pwT, const float* __restrict__ pb, float* __restrict__ out){
  int b = blockIdx.x >> 7, tt = blockIdx.x & 127;
  __shared__ float xs[32][260];  // out_tok tile
  __shared__ float cs[8][516];   // centers_out for this b
  int tid = threadIdx.x;
  for (int k = 0; k < 16; k++){
    int i = k * 256 + tid;
    cs[i >> 9][i & 511] = cout[(size_t)b * 4096 + i];
  }
  __syncthreads();
  int r = tid >> 3, h = tid & 7;
  int t0 = tt * 32 + r;
  size_t so = (size_t)(b * N_H + h) * T_SZ + t0;
  int m1 = selm[so * 2], m2 = selm[so * 2 + 1];
  float2 w = selw[so];
#pragma unroll
  for (int d = 0; d < 32; d += 4){
    float4 c1 = *(const float4*)&cs[h][m1 * 32 + d];
    float4 c2 = *(const float4*)&cs[h][m2 * 32 + d];
    float4 o = make_float4(w.x * c1.x + w.y * c2.x, w.x * c1.y + w.y * c2.y,
                           w.x * c1.z + w.y * c2.z, w.x * c1.w + w.y * c2.w);
    *(float4*)&xs[r][h * 32 + d] = o;
  }
  __syncthreads();
  int tx = tid & 63, ty = tid >> 6;
  float acc[8][4];
#pragma unroll
  for (int rr = 0; rr < 8; rr++){ acc[rr][0] = 0.f; acc[rr][1] = 0.f; acc[rr][2] = 0.f; acc[rr][3] = 0.f; }
  gemm_inner(xs, pwT, tx, ty, acc);
  float4 bb = *(const float4*)(pb + tx * 4);
#pragma unroll
  for (int rr = 0; rr < 8; rr++){
    int t = tt * 32 + ty * 8 + rr;
    float4 o = make_float4(acc[rr][0] + bb.x, acc[rr][1] + bb.y, acc[rr][2] + bb.z, acc[rr][3] + bb.w);
    *(float4*)(out + ((size_t)t * B_SZ + b) * CIN + tx * 4) = o;
  }
}

extern "C" void kernel_launch(void* const* d_in, const int* in_sizes, int n_in,
                              void* d_out, int out_size, void* d_ws, size_t ws_size,
                              hipStream_t stream) {
  const float* x   = (const float*)d_in[0];
  const float* f_w = (const float*)d_in[1];
  const float* f_b = (const float*)d_in[2];
  const float* v_w = (const float*)d_in[3];
  const float* v_b = (const float*)d_in[4];
  const float* p_w = (const float*)d_in[5];
  const float* p_b = (const float*)d_in[6];
  const float* s_a = (const float*)d_in[7];
  const float* s_b = (const float*)d_in[8];
  float* out = (float*)d_out;
  char* ws = (char*)d_ws;

  float*  fwT  = (float*)(ws + O_FWT);
  float*  vwT  = (float*)(ws + O_VWT);
  float*  pwT  = (float*)(ws + O_PWT);
  double* px   = (double*)(ws + O_PX);
  double* c64  = (double*)(ws + O_C64);
  float*  c32  = (float*)(ws + O_C32);
  float*  vc   = (float*)(ws + O_VC);
  float*  cout = (float*)(ws + O_COUT);
  float*  gpart= (float*)(ws + O_GPART);
  int*    cnt  = (int*)(ws + O_CNT);
  unsigned int* list = (unsigned int*)(ws + O_LIST);
  u8*     selm = (u8*)(ws + O_SELM);
  float2* selw = (float2*)(ws + O_SELW);
  float*  v    = (float*)(ws + O_V);

  hipMemsetAsync(ws + O_CNT, 0, 256, stream);
  k_transpose<<<768, 256, 0, stream>>>(f_w, v_w, p_w, fwT, vwT, pwT);
  k_pool<<<256, 256, 0, stream>>>(x, px);
  k_centers<<<256, 256, 0, stream>>>(px, fwT, vwT, f_b, v_b, c64, c32, vc);
  k_qsim<<<2048, 256, 0, stream>>>(x, fwT, f_b, c32, s_a, s_b, selm, selw, cnt, list);
  k_vgemm<<<2048, 256, 0, stream>>>(x, vwT, v_b, v);
  k_rescue<<<256, 256, 0, stream>>>(x, f_w, f_b, c64, s_a, s_b, cnt, list, selm, selw);
  k_scatter<<<1024, 256, 0, stream>>>(v, selm, selw, gpart);
  k_cfinal<<<256, 256, 0, stream>>>(gpart, vc, cout);
  k_proj<<<2048, 256, 0, stream>>>(cout, selm, selw, pwT, p_b, out);
}

// Round 4
// 399.401 us; speedup vs baseline: 2.3504x; 1.3775x over previous
//
#include <hip/hip_runtime.h>
#include <math.h>

#define T_SZ 4096
#define B_SZ 16
#define CIN 256
#define N_H 8
#define D_H 32
#define M_C 16
#define TAU 5e-5f
#define RCAP (1<<19)

typedef unsigned char u8;
typedef unsigned int uint;
typedef unsigned short ushort;

using frag_ab = __attribute__((ext_vector_type(8))) short;   // 8 bf16 (4 VGPRs)
using frag_c  = __attribute__((ext_vector_type(4))) float;   // 4 fp32 acc

// ---- workspace layout (bytes) ----
#define O_FWT   0         // float[256*256] f_w^T [c][j] (for k_centers)
#define O_VWT   262144    // float[256*256]
#define O_WFH   524288    // bf16[256n][256k] f_w hi (natural [j][c] layout)
#define O_WFL   655360
#define O_WVH   786432
#define O_WVL   917504
#define O_WPH   1048576
#define O_WPL   1179648
#define O_PX    1310720   // double[B*16*256]
#define O_C64   1835008   // double[128*16*32] normalized centers
#define O_C32   2359296   // float same
#define O_VC    2621440   // float value centers
#define O_COUT  2883584   // float centers_out
#define O_GPART 3145728   // float[128*8*528]
#define O_CNT   5308416   // int rescue counter
#define O_LIST  5308672   // uint[RCAP]
#define O_SELM  7405824   // u8[128*4096*2]
#define O_SELW  8454400   // float2[128*4096]
#define O_V     12648704  // float[16][4096][256]; out_tok (fp32) OVERLAYS this after scatter
// end = 79757568 (~76 MB, same as proven round-3 budget)

__device__ __forceinline__ uint bfr(float f){          // fp32 -> bf16 bits, RNE
  uint u = __float_as_uint(f);
  return (u + 0x7FFFu + ((u >> 16) & 1u)) >> 16;
}
__device__ __forceinline__ float bff(uint h){ return __uint_as_float(h << 16); }

// ---------------- weight transpose (fp32, for fp64 centers kernel) ----------------
__global__ void k_transpose(const float* __restrict__ fw, const float* __restrict__ vw,
                            float* __restrict__ fwT, float* __restrict__ vwT){
  int id = blockIdx.x * 256 + threadIdx.x;
  int mat = id >> 16; int rem = id & 65535;
  int j = rem >> 8, c = rem & 255;
  const float* src = (mat == 0) ? fw : vw;
  float* dst = (mat == 0) ? fwT : vwT;
  dst[c * 256 + j] = src[j * 256 + c];
}

// ---------------- weight bf16 hi/lo split (natural [n][k] layout) ----------------
__global__ void k_wsplit(const float* __restrict__ fw, const float* __restrict__ vw,
                         const float* __restrict__ pw,
                         ushort* __restrict__ fh, ushort* __restrict__ fl,
                         ushort* __restrict__ vh, ushort* __restrict__ vl,
                         ushort* __restrict__ ph, ushort* __restrict__ pl){
  int id = blockIdx.x * 256 + threadIdx.x;   // 3*65536
  int mat = id >> 16, rem = id & 65535;
  const float* s = (mat == 0) ? fw : ((mat == 1) ? vw : pw);
  ushort* dh = (mat == 0) ? fh : ((mat == 1) ? vh : ph);
  ushort* dl = (mat == 0) ? fl : ((mat == 1) ? vl : pl);
  float a = s[rem];
  uint h = bfr(a);
  dh[rem] = (ushort)h;
  dl[rem] = (ushort)bfr(a - bff(h));
}

// ---------------- fp64 spatial pooling of x ----------------
__global__ void k_pool(const float* __restrict__ x, double* __restrict__ px){
  int b = blockIdx.x >> 4, m = blockIdx.x & 15;
  int pr = m >> 2, pc = m & 3;
  int c = threadIdx.x;
  double s = 0.0;
  for (int i = 0; i < 16; i++){
    int t0 = (pr * 16 + i) * 64 + pc * 16;
    const float* xr = x + ((size_t)t0 * B_SZ + b) * CIN + c;
    for (int jj = 0; jj < 16; jj++)
      s += (double)xr[(size_t)jj * B_SZ * CIN];
  }
  px[(size_t)(b * 16 + m) * 256 + c] = s * (1.0 / 256.0);
}

// ---------------- fp64 centers + value centers ----------------
__global__ void k_centers(const double* __restrict__ px, const float* __restrict__ fwT,
                          const float* __restrict__ vwT, const float* __restrict__ fb,
                          const float* __restrict__ vb, double* __restrict__ c64,
                          float* __restrict__ c32, float* __restrict__ vc){
  int b = blockIdx.x >> 4, m = blockIdx.x & 15;
  int j = threadIdx.x;
  const double* pxr = px + (size_t)(b * 16 + m) * 256;
  double cq = (double)fb[j], cv = (double)vb[j];
  for (int c = 0; c < 256; c++){
    double p = pxr[c];
    cq += p * (double)fwT[c * 256 + j];
    cv += p * (double)vwT[c * 256 + j];
  }
  __shared__ double sq[256];
  __shared__ double snm[8];
  sq[j] = cq * cq;
  __syncthreads();
  int h = j >> 5, d = j & 31;
  if ((j & 31) == 0){
    double ts = 0.0;
    for (int dd = 0; dd < 32; dd++) ts += sq[h * 32 + dd];
    snm[h] = fmax(sqrt(ts), 1e-12);
  }
  __syncthreads();
  double nm = snm[h];
  size_t o = ((size_t)(b * N_H + h) * M_C + m) * D_H + d;
  double ch = cq / nm;
  c64[o] = ch; c32[o] = (float)ch; vc[o] = (float)cv;
}

// ================= MFMA GEMM core: 128x128 tile, K=256, BK=32, bf16 3-term =================
// LDS ushort tiles at padded stride 40 (80B rows -> <=2-way bank aliasing on b128 frag reads).
#define LSTR 40
#define LTILE (128 * LSTR)   // 5120 ushorts per tile

__device__ __forceinline__ void stage_tiles(
    const float* __restrict__ A, size_t aBase, int aStride, int kk,
    const ushort* __restrict__ Bh, const ushort* __restrict__ Bl,
    ushort* Ah, ushort* Al, ushort* Bhs, ushort* Bls, int tid){
#pragma unroll
  for (int rep = 0; rep < 2; rep++){
    int part = tid + rep * 256;
    int row = part >> 2, q4 = part & 3;
    // A: 8 fp32 -> bf16 hi/lo
    const float* ga = A + aBase + (size_t)row * aStride + kk * 32 + q4 * 8;
    float4 a0 = *(const float4*)ga;
    float4 a1 = *(const float4*)(ga + 4);
    uint h0 = bfr(a0.x), h1 = bfr(a0.y), h2 = bfr(a0.z), h3 = bfr(a0.w);
    uint h4 = bfr(a1.x), h5 = bfr(a1.y), h6 = bfr(a1.z), h7 = bfr(a1.w);
    uint l0 = bfr(a0.x - bff(h0)), l1 = bfr(a0.y - bff(h1));
    uint l2 = bfr(a0.z - bff(h2)), l3 = bfr(a0.w - bff(h3));
    uint l4 = bfr(a1.x - bff(h4)), l5 = bfr(a1.y - bff(h5));
    uint l6 = bfr(a1.z - bff(h6)), l7 = bfr(a1.w - bff(h7));
    uint4 hv = make_uint4(h0 | (h1 << 16), h2 | (h3 << 16), h4 | (h5 << 16), h6 | (h7 << 16));
    uint4 lv = make_uint4(l0 | (l1 << 16), l2 | (l3 << 16), l4 | (l5 << 16), l6 | (l7 << 16));
    *(uint4*)&Ah[row * LSTR + q4 * 8] = hv;
    *(uint4*)&Al[row * LSTR + q4 * 8] = lv;
    // B: already bf16, [n][k] contiguous
    size_t bo = (size_t)row * 256 + kk * 32 + q4 * 8;
    *(uint4*)&Bhs[row * LSTR + q4 * 8] = *(const uint4*)(Bh + bo);
    *(uint4*)&Bls[row * LSTR + q4 * 8] = *(const uint4*)(Bl + bo);
  }
}

__device__ __forceinline__ void compute_step(
    const ushort* Ah, const ushort* Al, const ushort* Bhs, const ushort* Bls,
    int wm, int wn, int li, int quad, frag_c acc[4][4]){
  frag_ab ah[4], al[4], bh[4], bl[4];
#pragma unroll
  for (int m = 0; m < 4; m++){
    int off = (wm * 64 + m * 16 + li) * LSTR + quad * 8;
    ah[m] = *(const frag_ab*)&Ah[off];
    al[m] = *(const frag_ab*)&Al[off];
  }
#pragma unroll
  for (int n = 0; n < 4; n++){
    int off = (wn * 64 + n * 16 + li) * LSTR + quad * 8;
    bh[n] = *(const frag_ab*)&Bhs[off];
    bl[n] = *(const frag_ab*)&Bls[off];
  }
#pragma unroll
  for (int m = 0; m < 4; m++)
#pragma unroll
    for (int n = 0; n < 4; n++){
      acc[m][n] = __builtin_amdgcn_mfma_f32_16x16x32_bf16(ah[m], bh[n], acc[m][n], 0, 0, 0);
      acc[m][n] = __builtin_amdgcn_mfma_f32_16x16x32_bf16(ah[m], bl[n], acc[m][n], 0, 0, 0);
      acc[m][n] = __builtin_amdgcn_mfma_f32_16x16x32_bf16(al[m], bh[n], acc[m][n], 0, 0, 0);
    }
}

__device__ __forceinline__ void gemm_core(
    const float* __restrict__ A, size_t aBase, int aStride,
    const ushort* __restrict__ Bh, const ushort* __restrict__ Bl,
    ushort* SM, frag_c acc[4][4], int tid){
  ushort* Ah = SM;             ushort* Al = SM + LTILE;
  ushort* Bhs = SM + 2*LTILE;  ushort* Bls = SM + 3*LTILE;
  int li = tid & 15, quad = (tid & 63) >> 4;
  int w = tid >> 6, wm = w >> 1, wn = w & 1;
#pragma unroll
  for (int m = 0; m < 4; m++)
#pragma unroll
    for (int n = 0; n < 4; n++)
      acc[m][n] = frag_c{0.f, 0.f, 0.f, 0.f};
  for (int kk = 0; kk < 8; kk++){
    __syncthreads();
    stage_tiles(A, aBase, aStride, kk, Bh, Bl, Ah, Al, Bhs, Bls, tid);
    __syncthreads();
    compute_step(Ah, Al, Bhs, Bls, wm, wn, li, quad, acc);
  }
}

// ---------------- GEMM + plain store (v-GEMM and proj-GEMM) ----------------
__global__ __launch_bounds__(256, 3) void k_gemm_store(
    const float* __restrict__ A, int aStride, int aBMul,
    const ushort* __restrict__ Bh, const ushort* __restrict__ Bl,
    const float* __restrict__ bias,
    float* __restrict__ Out, int oStride, int oBMul){
  int bx = blockIdx.x;
  int nt = bx & 1, mt = (bx >> 1) & 31, b = bx >> 6;
  __shared__ ushort SM[4 * LTILE];
  frag_c acc[4][4];
  int tid = threadIdx.x;
  size_t aBase = (size_t)b * aBMul + (size_t)(mt * 128) * aStride;
  const ushort* Bhp = Bh + (size_t)(nt * 128) * 256;
  const ushort* Blp = Bl + (size_t)(nt * 128) * 256;
  gemm_core(A, aBase, aStride, Bhp, Blp, SM, acc, tid);

  int li = tid & 15, quad = (tid & 63) >> 4;
  int w = tid >> 6, wm = w >> 1, wn = w & 1;
  int colBase = nt * 128 + wn * 64 + li;
  float bn[4];
#pragma unroll
  for (int n = 0; n < 4; n++) bn[n] = bias[colBase + n * 16];
#pragma unroll
  for (int m = 0; m < 4; m++){
    int row0 = mt * 128 + wm * 64 + m * 16 + quad * 4;
#pragma unroll
    for (int n = 0; n < 4; n++){
      int col = colBase + n * 16;
#pragma unroll
      for (int r = 0; r < 4; r++)
        Out[(size_t)(row0 + r) * oStride + (size_t)b * oBMul + col] = acc[m][n][r] + bn[n];
    }
  }
}

// ---------------- GEMM + fused similarity/top-2 epilogue (q path) ----------------
__global__ __launch_bounds__(256, 2) void k_gemm_qsim(
    const float* __restrict__ A, int aStride, int aBMul,
    const ushort* __restrict__ Bh, const ushort* __restrict__ Bl,
    const float* __restrict__ bias, const float* __restrict__ c32,
    const float* __restrict__ salpha, const float* __restrict__ sbeta,
    u8* __restrict__ selm, float2* __restrict__ selw,
    int* __restrict__ cnt, unsigned int* __restrict__ list){
  int bx = blockIdx.x;
  int nt = bx & 1, mt = (bx >> 1) & 31, b = bx >> 6;
  __shared__ ushort SM[4 * LTILE];
  __shared__ float cs[4][520];    // this block's 4 heads' normalized centers
  frag_c acc[4][4];
  int tid = threadIdx.x;
  // load centers (heads nt*4 .. nt*4+3)
  for (int i = tid; i < 2048; i += 256){
    int hh = i >> 9, rem = i & 511;
    cs[hh][rem] = c32[(size_t)b * 4096 + (nt * 4 + hh) * 512 + rem];
  }
  size_t aBase = (size_t)b * aBMul + (size_t)(mt * 128) * aStride;
  const ushort* Bhp = Bh + (size_t)(nt * 128) * 256;
  const ushort* Blp = Bl + (size_t)(nt * 128) * 256;
  gemm_core(A, aBase, aStride, Bhp, Blp, SM, acc, tid);

  int li = tid & 15, quad = (tid & 63) >> 4;
  int w = tid >> 6, wm = w >> 1, wn = w & 1;
  int colBase = nt * 128 + wn * 64 + li;
  float bn[4];
#pragma unroll
  for (int n = 0; n < 4; n++) bn[n] = bias[colBase + n * 16];
  float alpha = salpha[0], beta = sbeta[0];
  float* qbuf = (float*)SM;       // 64 x 132 fp32 = 33792 B <= 40960 B
  for (int half = 0; half < 2; half++){
    __syncthreads();
    if (wm == half){
#pragma unroll
      for (int m = 0; m < 4; m++)
#pragma unroll
        for (int n = 0; n < 4; n++)
#pragma unroll
          for (int r = 0; r < 4; r++)
            qbuf[(m * 16 + quad * 4 + r) * 132 + wn * 64 + n * 16 + li] = acc[m][n][r] + bn[n];
    }
    __syncthreads();
    // sim for 64 tokens x 4 heads (one per thread)
    int tok = tid >> 2, hh = tid & 3;
    int t = mt * 128 + half * 64 + tok;
    int h = nt * 4 + hh;
    float q[32];
    float ss = 0.f;
#pragma unroll
    for (int d = 0; d < 32; d += 4){
      float4 qv = *(const float4*)&qbuf[tok * 132 + hh * 32 + d];
      q[d] = qv.x; q[d + 1] = qv.y; q[d + 2] = qv.z; q[d + 3] = qv.w;
      ss += qv.x * qv.x + qv.y * qv.y + qv.z * qv.z + qv.w * qv.w;
    }
    float inv = 1.f / fmaxf(sqrtf(ss), 1e-12f);
    float s1 = -1e30f, s2 = -1e30f, s3 = -1e30f; int i1 = 0, i2 = 0;
#pragma unroll
    for (int m = 0; m < 16; m++){
      float dot = 0.f;
#pragma unroll
      for (int d = 0; d < 32; d += 4){
        float4 cv = *(const float4*)&cs[hh][m * 32 + d];
        dot = fmaf(q[d], cv.x, fmaf(q[d + 1], cv.y, fmaf(q[d + 2], cv.z, fmaf(q[d + 3], cv.w, dot))));
      }
      float z = beta + alpha * (dot * inv);
      float s = 1.f / (1.f + expf(-z));
      if (s > s1){ s3 = s2; s2 = s1; i2 = i1; s1 = s; i1 = m; }
      else if (s > s2){ s3 = s2; s2 = s; i2 = m; }
      else if (s > s3){ s3 = s; }
    }
    if (s2 - s3 < TAU){
      int idx = atomicAdd(cnt, 1);
      if (idx < RCAP) list[idx] = (((unsigned)(b * N_H + h)) << 12) | (unsigned)t;
    }
    float r1 = s1 * s1, r2 = s2 * s2;
    float den = r1 + r2 + 1e-6f;
    size_t so = (size_t)(b * N_H + h) * T_SZ + t;
    selm[so * 2] = (u8)i1; selm[so * 2 + 1] = (u8)i2;
    selw[so] = make_float2(r1 / den, r2 / den);
  }
}

// ---------------- fp64 rescue for near-tie tokens: ONE WAVE PER TOKEN ----------------
__global__ __launch_bounds__(256, 4) void k_rescue(
    const float* __restrict__ x, const float* __restrict__ fw, const float* __restrict__ fb,
    const double* __restrict__ c64, const float* __restrict__ salpha, const float* __restrict__ sbeta,
    const int* __restrict__ cnt, const unsigned int* __restrict__ list,
    u8* __restrict__ selm, float2* __restrict__ selw){
  int n = *cnt; if (n > RCAP) n = RCAP;
  int lane = threadIdx.x & 63;
  int wid = (blockIdx.x * 256 + threadIdx.x) >> 6;
  int nw = gridDim.x * 4;
  double alpha = (double)salpha[0], beta = (double)sbeta[0];
  for (int i = wid; i < n; i += nw){
    unsigned e = list[i];
    int t = e & 4095; int bh = e >> 12; int b = bh >> 3, h = bh & 7;
    int d = lane & 31, half = lane >> 5;
    const float* xh = x + ((size_t)t * B_SZ + b) * CIN + half * 128;
    const float* wr = fw + (size_t)(h * 32 + d) * CIN + half * 128;
    double a0 = 0, a1 = 0, a2 = 0, a3 = 0;
#pragma unroll 4
    for (int c = 0; c < 128; c += 4){
      float4 xv = *(const float4*)(xh + c);
      float4 wv = *(const float4*)(wr + c);
      a0 += (double)xv.x * (double)wv.x;
      a1 += (double)xv.y * (double)wv.y;
      a2 += (double)xv.z * (double)wv.z;
      a3 += (double)xv.w * (double)wv.w;
    }
    double qd = (a0 + a1) + (a2 + a3);
    qd += __shfl_down(qd, 32);
    if (lane < 32) qd += (double)fb[h * 32 + d];
    else qd = 0.0;
    double ss = qd * qd;
#pragma unroll
    for (int off = 32; off; off >>= 1) ss += __shfl_xor(ss, off);
    double inv = 1.0 / fmax(sqrt(ss), 1e-12);
    const double* cb = c64 + (size_t)bh * (M_C * D_H);
    int m = lane & 15;
    double dot = 0.0;
#pragma unroll
    for (int dd = 0; dd < 32; dd++){
      double qv = __shfl(qd, dd);
      dot += qv * cb[m * 32 + dd];
    }
    double z = beta + alpha * (dot * inv);
    double s = 1.0 / (1.0 + exp(-z));
    double s1 = -1e300, s2 = -1e300; int i1 = 0, i2 = 0;
#pragma unroll
    for (int mm = 0; mm < 16; mm++){
      double sv = __shfl(s, mm);
      if (sv > s1){ s2 = s1; i2 = i1; s1 = sv; i1 = mm; }
      else if (sv > s2){ s2 = sv; i2 = mm; }
    }
    if (lane == 0){
      double r1 = s1 * s1, r2 = s2 * s2, den = r1 + r2 + 1e-6;
      size_t so = (size_t)bh * T_SZ + t;
      selm[so * 2] = (u8)i1; selm[so * 2 + 1] = (u8)i2;
      selw[so] = make_float2((float)(r1 / den), (float)(r2 / den));
    }
  }
}

// ---------------- scatter: ownership-transposed, NO atomics ----------------
__global__ __launch_bounds__(256, 4) void k_scatter(
    const float* __restrict__ v, const u8* __restrict__ selm, const float2* __restrict__ selw,
    float* __restrict__ gpart){
  int bh = blockIdx.x >> 3, chunk = blockIdx.x & 7;
  int b = bh >> 3, h = bh & 7;
  int tid = threadIdx.x;
  int mA = tid >> 5, mB = mA + 8, d = tid & 31;
  __shared__ uchar2 sm[512];
  __shared__ float2 sw[512];
  for (int i = tid; i < 512; i += 256){
    size_t so = (size_t)bh * T_SZ + chunk * 512 + i;
    sm[i] = make_uchar2(selm[so * 2], selm[so * 2 + 1]);
    sw[i] = selw[so];
  }
  __syncthreads();
  const float* vb = v + ((size_t)b * T_SZ + chunk * 512) * CIN + h * 32 + d;
  float accA = 0.f, accB = 0.f, cntA = 0.f, cntB = 0.f;
#pragma unroll 8
  for (int i = 0; i < 512; i++){
    float vv = vb[(size_t)i * CIN];
    uchar2 mm = sm[i];
    float2 w = sw[i];
    float wA = (mm.x == mA) ? w.x : ((mm.y == mA) ? w.y : 0.f);
    float wB = (mm.x == mB) ? w.x : ((mm.y == mB) ? w.y : 0.f);
    accA = fmaf(wA, vv, accA); cntA += wA;
    accB = fmaf(wB, vv, accB); cntB += wB;
  }
  float* gp = gpart + (size_t)(bh * 8 + chunk) * 528;
  gp[mA * 33 + d] = accA;
  gp[mB * 33 + d] = accB;
  if (d == 0){ gp[mA * 33 + 32] = cntA; gp[mB * 33 + 32] = cntB; }
}

// ---------------- centers_out finalize ----------------
__global__ void k_cfinal(const float* __restrict__ gpart, const float* __restrict__ vc,
                         float* __restrict__ cout){
  int id = blockIdx.x * 256 + threadIdx.x;
  int bh = id >> 9, rem = id & 511, m = rem >> 5, d = rem & 31;
  float num = 0.f, den = 0.f;
#pragma unroll
  for (int c = 0; c < 8; c++){
    const float* gp = gpart + (size_t)(bh * 8 + c) * 528 + m * 33;
    num += gp[d];
    den += gp[32];
  }
  cout[id] = (num + vc[id]) / (den + 1.0f);
}

// ---------------- build out_tok fp32 [b][t][c] ----------------
__global__ __launch_bounds__(256, 4) void k_mix(
    const float* __restrict__ cout, const u8* __restrict__ selm, const float2* __restrict__ selw,
    float* __restrict__ OT){
  int b = blockIdx.x >> 7, tt = blockIdx.x & 127;
  __shared__ float cs[8][516];
  int tid = threadIdx.x;
  for (int k = 0; k < 16; k++){
    int i = k * 256 + tid;
    cs[i >> 9][i & 511] = cout[(size_t)b * 4096 + i];
  }
  __syncthreads();
  int r = tid >> 3, h = tid & 7;
  int t = tt * 32 + r;
  size_t so = (size_t)(b * N_H + h) * T_SZ + t;
  int m1 = selm[so * 2], m2 = selm[so * 2 + 1];
  float2 w = selw[so];
#pragma unroll
  for (int d = 0; d < 32; d += 4){
    float4 c1 = *(const float4*)&cs[h][m1 * 32 + d];
    float4 c2 = *(const float4*)&cs[h][m2 * 32 + d];
    float4 o = make_float4(w.x * c1.x + w.y * c2.x, w.x * c1.y + w.y * c2.y,
                           w.x * c1.z + w.y * c2.z, w.x * c1.w + w.y * c2.w);
    *(float4*)&OT[((size_t)b * T_SZ + t) * CIN + h * 32 + d] = o;
  }
}

extern "C" void kernel_launch(void* const* d_in, const int* in_sizes, int n_in,
                              void* d_out, int out_size, void* d_ws, size_t ws_size,
                              hipStream_t stream) {
  const float* x   = (const float*)d_in[0];
  const float* f_w = (const float*)d_in[1];
  const float* f_b = (const float*)d_in[2];
  const float* v_w = (const float*)d_in[3];
  const float* v_b = (const float*)d_in[4];
  const float* p_w = (const float*)d_in[5];
  const float* p_b = (const float*)d_in[6];
  const float* s_a = (const float*)d_in[7];
  const float* s_b = (const float*)d_in[8];
  float* out = (float*)d_out;
  char* ws = (char*)d_ws;

  float*  fwT  = (float*)(ws + O_FWT);
  float*  vwT  = (float*)(ws + O_VWT);
  ushort* wfh  = (ushort*)(ws + O_WFH);
  ushort* wfl  = (ushort*)(ws + O_WFL);
  ushort* wvh  = (ushort*)(ws + O_WVH);
  ushort* wvl  = (ushort*)(ws + O_WVL);
  ushort* wph  = (ushort*)(ws + O_WPH);
  ushort* wpl  = (ushort*)(ws + O_WPL);
  double* px   = (double*)(ws + O_PX);
  double* c64  = (double*)(ws + O_C64);
  float*  c32  = (float*)(ws + O_C32);
  float*  vc   = (float*)(ws + O_VC);
  float*  cout = (float*)(ws + O_COUT);
  float*  gpart= (float*)(ws + O_GPART);
  int*    cnt  = (int*)(ws + O_CNT);
  unsigned int* list = (unsigned int*)(ws + O_LIST);
  u8*     selm = (u8*)(ws + O_SELM);
  float2* selw = (float2*)(ws + O_SELW);
  float*  v    = (float*)(ws + O_V);
  float*  OT   = (float*)(ws + O_V);   // overlay: v dead after k_scatter

  hipMemsetAsync(ws + O_CNT, 0, 256, stream);
  k_transpose<<<512, 256, 0, stream>>>(f_w, v_w, fwT, vwT);
  k_wsplit<<<768, 256, 0, stream>>>(f_w, v_w, p_w, wfh, wfl, wvh, wvl, wph, wpl);
  k_pool<<<256, 256, 0, stream>>>(x, px);
  k_centers<<<256, 256, 0, stream>>>(px, fwT, vwT, f_b, v_b, c64, c32, vc);
  // q-GEMM + fused sim: A = x [t][b][c] (row t stride 4096 floats, batch offset 256 floats)
  k_gemm_qsim<<<1024, 256, 0, stream>>>(x, 4096, 256, wfh, wfl, f_b, c32, s_a, s_b,
                                        selm, selw, cnt, list);
  // v-GEMM: out v[b][t][c]
  k_gemm_store<<<1024, 256, 0, stream>>>(x, 4096, 256, wvh, wvl, v_b, v, 256, T_SZ * CIN);
  k_rescue<<<256, 256, 0, stream>>>(x, f_w, f_b, c64, s_a, s_b, cnt, list, selm, selw);
  k_scatter<<<1024, 256, 0, stream>>>(v, selm, selw, gpart);
  k_cfinal<<<256, 256, 0, stream>>>(gpart, vc, cout);
  k_mix<<<2048, 256, 0, stream>>>(cout, selm, selw, OT);
  // proj-GEMM: A = OT [b][t][c] (row stride 256, batch offset 4096*256); out [t][b][c]
  k_gemm_store<<<1024, 256, 0, stream>>>(OT, 256, T_SZ * CIN, wph, wpl, p_b, out, 4096, 256);
}